// Round 3
// baseline (39.747 us; speedup 1.0000x reference)
//
#include <hip/hip_runtime.h>

#define NB 2
#define C 32
#define H 128
#define W 256
#define D 48
#define HW (H * W)

// ---------------------------------------------------------------------------
// zkern v3: z[n][d][h][w] = sum_c x[n][c][h][w] * y[n][c][h][w-d]  (0 if w<d)
// Grid NB*H (=256) blocks x 384 threads (6 waves).
// Thread = (w-quad q 0..63, dgroup dg 0..5); dgroup owns d0=8*dg .. d0+7.
// y row staged in LDS with 48-float zero left-pad. Per c: one aligned
// 12-float window (3 x ds_read_b128, lane-contiguous => conflict-free)
// serves 4w x 8d = 32 FMAs.
// ---------------------------------------------------------------------------
__global__ __launch_bounds__(384) void zkern(const float* __restrict__ x,
                                             const float* __restrict__ y,
                                             float* __restrict__ z) {
    const int nh  = blockIdx.x;
    const int n   = nh / H;
    const int h   = nh % H;
    const int tid = threadIdx.x;
    const int q   = tid & 63;    // w-quad: w = 4q..4q+3
    const int dg  = tid >> 6;    // 0..5
    const int d0  = dg * 8;

    __shared__ __align__(16) float ys[C][304];  // [0..47]=0 pad, [48+w]=y[c][w]

    const float* xrow = x + ((size_t)(n * C) * H + h) * (size_t)W;
    const float* yrow = y + ((size_t)(n * C) * H + h) * (size_t)W;

    // stage: 32 rows x 76 float4 (first 12 f4 of each row = zero pad)
#pragma unroll
    for (int it = 0; it < 7; ++it) {
        const int idx = it * 384 + tid;
        if (idx < 32 * 76) {
            const int r  = idx / 76;
            const int c4 = idx % 76;
            float4 v = {0.f, 0.f, 0.f, 0.f};
            if (c4 >= 12) v = *(const float4*)(yrow + (size_t)r * HW + 4 * (c4 - 12));
            *(float4*)&ys[r][4 * c4] = v;
        }
    }
    __syncthreads();

    float acc[8][4] = {};
    const int s = 4 * q + 40 - d0;   // window start (padded float idx), s%4==0

#pragma unroll 4
    for (int c = 0; c < C; ++c) {
        const float4 xv = *(const float4*)(xrow + (size_t)c * HW + 4 * q);
        const float4 w0 = *(const float4*)&ys[c][s];
        const float4 w1 = *(const float4*)&ys[c][s + 4];
        const float4 w2 = *(const float4*)&ys[c][s + 8];
        const float win[12] = {w0.x, w0.y, w0.z, w0.w,
                               w1.x, w1.y, w1.z, w1.w,
                               w2.x, w2.y, w2.z, w2.w};
        const float xs[4] = {xv.x, xv.y, xv.z, xv.w};
        // acc[k][o] += x[4q+o] * y[4q+o-(d0+k)] ; win[m] <-> y[4q-d0+m-8]
#pragma unroll
        for (int k = 0; k < 8; ++k)
#pragma unroll
            for (int o = 0; o < 4; ++o)
                acc[k][o] += xs[o] * win[8 + o - k];
    }

    float* zp = z + (((size_t)n * D + d0) * H + h) * (size_t)W + 4 * q;
#pragma unroll
    for (int k = 0; k < 8; ++k) {
        float4 v;
        v.x = acc[k][0]; v.y = acc[k][1]; v.z = acc[k][2]; v.w = acc[k][3];
        *(float4*)(zp + (size_t)k * HW) = v;
    }
}

// ---------------------------------------------------------------------------
// fkern v3: out[n][d][h][w] = bias + sum_{i,j} F[n][i*5+j][h][w] *
//                                          z[n][d][h+2(i-2)][w+2(j-2)]
// One block per (n,h) (grid 256), 512 threads = 64 w-quads x 8 dgroups.
// Thread owns 6 disparities d = 8*dj + g. Loop over filter row i:
//   stage z[n][all 48 d][h+2i-4][:] (w-padded +-4) into 50.7 KB LDS,
//   hold row-i taps (5 float4) in VGPRs across all 48 d,
//   read 12-float windows as 3 lane-contiguous ds_read_b128.
// ---------------------------------------------------------------------------
__global__ __launch_bounds__(512) void fkern(const float* __restrict__ z,
                                             const float* __restrict__ Ff,
                                             const float* __restrict__ B,
                                             float* __restrict__ out) {
    __shared__ __align__(16) float zs[D][264];   // col 0 <-> w=-4 ; cols 4..259 valid

    const int nh  = blockIdx.x;
    const int n   = nh / H;
    const int h   = nh % H;
    const int tid = threadIdx.x;
    const int q   = tid & 63;    // w-quad
    const int g   = tid >> 6;    // 0..7

    const float4 bias = *(const float4*)(B + ((size_t)n * H + h) * (size_t)W + 4 * q);
    float acc[6][4];
#pragma unroll
    for (int dj = 0; dj < 6; ++dj) {
        acc[dj][0] = bias.x; acc[dj][1] = bias.y;
        acc[dj][2] = bias.z; acc[dj][3] = bias.w;
    }

    for (int i = 0; i < 5; ++i) {
        const int hh = h + 2 * i - 4;
        if (hh < 0 || hh >= H) continue;          // block-uniform

        // stage all 48 z-rows at height hh: 48 x 66 float4
#pragma unroll
        for (int it = 0; it < 7; ++it) {
            const int idx = it * 512 + tid;
            if (idx < 48 * 66) {
                const int r  = idx / 66;
                const int c4 = idx % 66;
                float4 v = {0.f, 0.f, 0.f, 0.f};
                if (c4 >= 1 && c4 <= 64)
                    v = *(const float4*)(z + (((size_t)n * D + r) * H + hh) * (size_t)W
                                           + 4 * c4 - 4);
                *(float4*)&zs[r][4 * c4] = v;
            }
        }
        __syncthreads();

        // row-i taps for this thread's 4 w
        float4 f[5];
#pragma unroll
        for (int jj = 0; jj < 5; ++jj)
            f[jj] = *(const float4*)(Ff + (((size_t)n * 25 + i * 5 + jj) * H + h) * (size_t)W
                                        + 4 * q);
        const float fs[5][4] = {
            {f[0].x, f[0].y, f[0].z, f[0].w},
            {f[1].x, f[1].y, f[1].z, f[1].w},
            {f[2].x, f[2].y, f[2].z, f[2].w},
            {f[3].x, f[3].y, f[3].z, f[3].w},
            {f[4].x, f[4].y, f[4].z, f[4].w}};

#pragma unroll
        for (int dj = 0; dj < 6; ++dj) {
            const int d = 8 * dj + g;
            const float4 w0 = *(const float4*)&zs[d][4 * q];
            const float4 w1 = *(const float4*)&zs[d][4 * q + 4];
            const float4 w2 = *(const float4*)&zs[d][4 * q + 8];
            const float win[12] = {w0.x, w0.y, w0.z, w0.w,
                                   w1.x, w1.y, w1.z, w1.w,
                                   w2.x, w2.y, w2.z, w2.w};
            // out[w=4q+o] += f[i5+jj][w] * z[d][hh][w+2jj-4] ; win[m]<->w=4q+m-4
#pragma unroll
            for (int jj = 0; jj < 5; ++jj)
#pragma unroll
                for (int o = 0; o < 4; ++o)
                    acc[dj][o] += fs[jj][o] * win[o + 2 * jj];
        }
        __syncthreads();
    }

    float* op = out + ((size_t)n * D * H + h) * (size_t)W + 4 * q;
#pragma unroll
    for (int dj = 0; dj < 6; ++dj) {
        const int d = 8 * dj + g;
        float4 v;
        v.x = acc[dj][0]; v.y = acc[dj][1]; v.z = acc[dj][2]; v.w = acc[dj][3];
        *(float4*)(op + (size_t)d * HW) = v;
    }
}

// ---------------------------------------------------------------------------
// Fallback (workspace too small): fully fused naive version. Correctness only.
// ---------------------------------------------------------------------------
__global__ __launch_bounds__(256) void fused_naive(const float* __restrict__ x,
                                                   const float* __restrict__ y,
                                                   const float* __restrict__ Ff,
                                                   const float* __restrict__ B,
                                                   float* __restrict__ out) {
    const size_t idx = (size_t)blockIdx.x * 256 + threadIdx.x;
    if (idx >= (size_t)NB * D * H * W) return;
    const int w = (int)(idx % W);
    const int h = (int)((idx / W) % H);
    const int d = (int)((idx / ((size_t)W * H)) % D);
    const int n = (int)(idx / ((size_t)W * H * D));

    float acc = B[((size_t)n * H + h) * W + w];
#pragma unroll
    for (int i = 0; i < 5; ++i) {
        const int hh = h + 2 * i - 4;
        if (hh < 0 || hh >= H) continue;
#pragma unroll
        for (int j = 0; j < 5; ++j) {
            const int ww = w + 2 * j - 4;
            if (ww < 0 || ww >= W) continue;
            const int ws_ = ww - d;
            float zv = 0.f;
            if (ws_ >= 0) {
                const float* xp = x + (((size_t)n * C) * H + hh) * (size_t)W + ww;
                const float* yp = y + (((size_t)n * C) * H + hh) * (size_t)W + ws_;
                for (int c = 0; c < C; ++c)
                    zv += xp[(size_t)c * HW] * yp[(size_t)c * HW];
            }
            acc += Ff[(((size_t)n * 25 + i * 5 + j) * H + h) * (size_t)W + w] * zv;
        }
    }
    out[idx] = acc;
}

extern "C" void kernel_launch(void* const* d_in, const int* in_sizes, int n_in,
                              void* d_out, int out_size, void* d_ws, size_t ws_size,
                              hipStream_t stream) {
    const float* x = (const float*)d_in[0];
    const float* y = (const float*)d_in[1];
    const float* F = (const float*)d_in[2];
    const float* B = (const float*)d_in[3];
    float* out = (float*)d_out;

    const size_t zbytes = (size_t)NB * D * H * W * sizeof(float);

    if (ws_size >= zbytes) {
        float* z = (float*)d_ws;
        zkern<<<NB * H, 384, 0, stream>>>(x, y, z);
        fkern<<<NB * H, 512, 0, stream>>>(z, F, B, out);
    } else {
        const size_t total = (size_t)NB * D * H * W;
        fused_naive<<<(int)((total + 255) / 256), 256, 0, stream>>>(x, y, F, B, out);
    }
}

// Round 4
// 32.712 us; speedup vs baseline: 1.2151x; 1.2151x over previous
//
#include <hip/hip_runtime.h>

#define NB 2
#define C 32
#define H 128
#define W 256
#define D 48
#define HW (H * W)

// ---------------------------------------------------------------------------
// zkern v4: z[n][d][h][w] = sum_c x[n][c][h][w] * y[n][c][h][w-d]  (0 if w<d)
// Grid NB*H*2 (=512 blocks, 2/CU, independent) x 192 threads.
// Block covers one w-half (128 w). Thread = (w-quad q 0..31, dgroup dg 0..5),
// dgroup owns d0=8*dg..d0+7. y staged in LDS cols [0,184): col = y_idx-128*half+48
// (cols<48-128*half are left zero-pad). Window start S0=4q+40-8dg is 16B-aligned
// -> exactly 3 ds_read_b128 per c serving 4w x 8d = 32 FMAs, static indices.
// ---------------------------------------------------------------------------
__global__ __launch_bounds__(192) void zkern(const float* __restrict__ x,
                                             const float* __restrict__ y,
                                             float* __restrict__ z) {
    const int b    = blockIdx.x;
    const int half = b & 1;
    const int nh   = b >> 1;
    const int n    = nh / H;
    const int h    = nh % H;
    const int tid  = threadIdx.x;
    const int q    = tid & 31;     // w-quad within half: w = 128*half + 4q + o
    const int dg   = tid >> 5;     // 0..5
    const int d0   = dg * 8;

    __shared__ __align__(16) float ys[C][184];   // col <-> y idx ybase+col

    const float* xrow = x + ((size_t)(n * C) * H + h) * (size_t)W;
    const float* yrow = y + ((size_t)(n * C) * H + h) * (size_t)W;
    const int ybase = 128 * half - 48;

    // stage: 32 rows x 46 float4 (zero where y idx OOB; cols>175 never read)
#pragma unroll
    for (int it = 0; it < 8; ++it) {
        const int idx = it * 192 + tid;
        if (idx < 32 * 46) {
            const int r    = idx / 46;
            const int c4   = idx % 46;
            const int yidx = ybase + 4 * c4;
            float4 v = {0.f, 0.f, 0.f, 0.f};
            if (yidx >= 0 && yidx <= W - 4)
                v = *(const float4*)(yrow + (size_t)r * HW + yidx);
            *(float4*)&ys[r][4 * c4] = v;
        }
    }
    __syncthreads();

    float acc[8][4] = {};
    const int S0 = 4 * q + 40 - d0;   // >= 0, 16B-aligned, S0+11 <= 175

#pragma unroll
    for (int c = 0; c < C; ++c) {
        const float4 xv = *(const float4*)(xrow + (size_t)c * HW + 128 * half + 4 * q);
        const float4 w0 = *(const float4*)&ys[c][S0];
        const float4 w1 = *(const float4*)&ys[c][S0 + 4];
        const float4 w2 = *(const float4*)&ys[c][S0 + 8];
        const float win[12] = {w0.x, w0.y, w0.z, w0.w,
                               w1.x, w1.y, w1.z, w1.w,
                               w2.x, w2.y, w2.z, w2.w};
        const float xs[4] = {xv.x, xv.y, xv.z, xv.w};
        // acc[k][o] += x[w] * y[w-(d0+k)] ; padded col = 4q+48+o-d -> win[8+o-k]
#pragma unroll
        for (int k = 0; k < 8; ++k)
#pragma unroll
            for (int o = 0; o < 4; ++o)
                acc[k][o] += xs[o] * win[8 + o - k];
    }

    float* zp = z + (((size_t)n * D + d0) * H + h) * (size_t)W + 128 * half + 4 * q;
#pragma unroll
    for (int k = 0; k < 8; ++k) {
        float4 v;
        v.x = acc[k][0]; v.y = acc[k][1]; v.z = acc[k][2]; v.w = acc[k][3];
        *(float4*)(zp + (size_t)k * HW) = v;
    }
}

// ---------------------------------------------------------------------------
// fkern v4: out[n][d][h][w] = bias + sum_{i,j} F[n][i*5+j][h][w] *
//                                          z[n][d][h+2(i-2)][w+2(j-2)]
// Grid NB*H*6 (=1536 blocks, 42KB LDS -> 3 resident/CU, 12 waves/CU) x 256 thr.
// Thread = (w-quad q 0..63, g 0..3), owns d = d0+g and d0+g+4.
// z slab (8d x 5 rows, cols 0..263 = w -4..259, OOB zero) staged via float4.
// Window = 3 lane-contiguous ds_read_b128 per (d,i); taps 25 float4/thread
// amortized over 2 d; i-loop fully unrolled so tap loads hoist.
// ---------------------------------------------------------------------------
#define DCH 8
#define NCH (D / DCH)   // 6

__global__ __launch_bounds__(256) void fkern(const float* __restrict__ z,
                                             const float* __restrict__ Ff,
                                             const float* __restrict__ B,
                                             float* __restrict__ out) {
    __shared__ __align__(16) float zs[DCH][5][264];   // col 0 <-> w=-4

    const int b  = blockIdx.x;
    const int ch = b % NCH;
    const int nh = b / NCH;
    const int n  = nh / H;
    const int h  = nh % H;
    const int tid = threadIdx.x;
    const int q  = tid & 63;    // w-quad: w = 4q+o
    const int g  = tid >> 6;    // 0..3
    const int d0 = ch * DCH;

    // stage: 40 rows x 66 float4
#pragma unroll
    for (int it = 0; it < 11; ++it) {
        const int idx = it * 256 + tid;
        if (idx < 40 * 66) {
            const int r  = idx / 66;
            const int c4 = idx % 66;
            const int dd = r / 5;
            const int i  = r % 5;
            const int hh = h + 2 * i - 4;
            float4 v = {0.f, 0.f, 0.f, 0.f};
            if (c4 >= 1 && c4 <= 64 && hh >= 0 && hh < H)
                v = *(const float4*)(z + (((size_t)n * D + d0 + dd) * H + hh) * (size_t)W
                                       + 4 * c4 - 4);
            *(float4*)&zs[dd][i][4 * c4] = v;
        }
    }

    const float4 bias = *(const float4*)(B + ((size_t)n * H + h) * (size_t)W + 4 * q);
    float acc[2][4];
#pragma unroll
    for (int kd = 0; kd < 2; ++kd) {
        acc[kd][0] = bias.x; acc[kd][1] = bias.y;
        acc[kd][2] = bias.z; acc[kd][3] = bias.w;
    }

    __syncthreads();

#pragma unroll
    for (int i = 0; i < 5; ++i) {
        float4 f[5];
#pragma unroll
        for (int jj = 0; jj < 5; ++jj)
            f[jj] = *(const float4*)(Ff + (((size_t)n * 25 + i * 5 + jj) * H + h) * (size_t)W
                                        + 4 * q);
        const float fs[5][4] = {
            {f[0].x, f[0].y, f[0].z, f[0].w},
            {f[1].x, f[1].y, f[1].z, f[1].w},
            {f[2].x, f[2].y, f[2].z, f[2].w},
            {f[3].x, f[3].y, f[3].z, f[3].w},
            {f[4].x, f[4].y, f[4].z, f[4].w}};

#pragma unroll
        for (int kd = 0; kd < 2; ++kd) {
            const int dd = g + 4 * kd;
            const float4 w0 = *(const float4*)&zs[dd][i][4 * q];
            const float4 w1 = *(const float4*)&zs[dd][i][4 * q + 4];
            const float4 w2 = *(const float4*)&zs[dd][i][4 * q + 8];
            const float win[12] = {w0.x, w0.y, w0.z, w0.w,
                                   w1.x, w1.y, w1.z, w1.w,
                                   w2.x, w2.y, w2.z, w2.w};
            // out[w=4q+o] += f[i*5+jj][w] * z[d][hh][w+2jj-4] ; padded col 4q+o+2jj
#pragma unroll
            for (int jj = 0; jj < 5; ++jj)
#pragma unroll
                for (int o = 0; o < 4; ++o)
                    acc[kd][o] += fs[jj][o] * win[o + 2 * jj];
        }
    }

#pragma unroll
    for (int kd = 0; kd < 2; ++kd) {
        float* op = out + (((size_t)n * D + d0 + g + 4 * kd) * H + h) * (size_t)W + 4 * q;
        float4 v;
        v.x = acc[kd][0]; v.y = acc[kd][1]; v.z = acc[kd][2]; v.w = acc[kd][3];
        *(float4*)op = v;
    }
}

// ---------------------------------------------------------------------------
// Fallback (workspace too small): fully fused naive version. Correctness only.
// ---------------------------------------------------------------------------
__global__ __launch_bounds__(256) void fused_naive(const float* __restrict__ x,
                                                   const float* __restrict__ y,
                                                   const float* __restrict__ Ff,
                                                   const float* __restrict__ B,
                                                   float* __restrict__ out) {
    const size_t idx = (size_t)blockIdx.x * 256 + threadIdx.x;
    if (idx >= (size_t)NB * D * H * W) return;
    const int w = (int)(idx % W);
    const int h = (int)((idx / W) % H);
    const int d = (int)((idx / ((size_t)W * H)) % D);
    const int n = (int)(idx / ((size_t)W * H * D));

    float acc = B[((size_t)n * H + h) * W + w];
#pragma unroll
    for (int i = 0; i < 5; ++i) {
        const int hh = h + 2 * i - 4;
        if (hh < 0 || hh >= H) continue;
#pragma unroll
        for (int j = 0; j < 5; ++j) {
            const int ww = w + 2 * j - 4;
            if (ww < 0 || ww >= W) continue;
            const int ws_ = ww - d;
            float zv = 0.f;
            if (ws_ >= 0) {
                const float* xp = x + (((size_t)n * C) * H + hh) * (size_t)W + ww;
                const float* yp = y + (((size_t)n * C) * H + hh) * (size_t)W + ws_;
                for (int c = 0; c < C; ++c)
                    zv += xp[(size_t)c * HW] * yp[(size_t)c * HW];
            }
            acc += Ff[(((size_t)n * 25 + i * 5 + j) * H + h) * (size_t)W + w] * zv;
        }
    }
    out[idx] = acc;
}

extern "C" void kernel_launch(void* const* d_in, const int* in_sizes, int n_in,
                              void* d_out, int out_size, void* d_ws, size_t ws_size,
                              hipStream_t stream) {
    const float* x = (const float*)d_in[0];
    const float* y = (const float*)d_in[1];
    const float* F = (const float*)d_in[2];
    const float* B = (const float*)d_in[3];
    float* out = (float*)d_out;

    const size_t zbytes = (size_t)NB * D * H * W * sizeof(float);

    if (ws_size >= zbytes) {
        float* z = (float*)d_ws;
        zkern<<<NB * H * 2, 192, 0, stream>>>(x, y, z);
        fkern<<<NB * H * NCH, 256, 0, stream>>>(z, F, B, out);
    } else {
        const size_t total = (size_t)NB * D * H * W;
        fused_naive<<<(int)((total + 255) / 256), 256, 0, stream>>>(x, y, F, B, out);
    }
}